// Round 7
// baseline (42443.991 us; speedup 1.0000x reference)
//
#include <hip/hip_runtime.h>
#include <math.h>

#define TT 2048
#define NB 64
#define EE 256
#define HH 256
#define NGRP 16   // batch groups (4 batches each)
#define PJ 16     // j-partitions (WGs) per group
#define JW 16     // j per WG
#define XLD 288   // swizzled row: 256 + 4 pad per 32 floats; phys(k)=k+(k>>5)*4

__device__ __forceinline__ float sigf(float x) { return 1.f / (1.f + expf(-x)); }

__device__ __forceinline__ unsigned long long packh(unsigned tag, float v) {
    union { float f; unsigned u; } c; c.f = v;
    return ((unsigned long long)tag << 32) | (unsigned long long)c.u;
}

// Persistent grouped LSTM: 256 WGs = 16 batch-groups x 16 j-slices, 1 WG/CU.
// R7: gate-colocated mapping. Thread = (jj, batch-pair, k-chunk); its 4 rows
// are i*16+jj (i = gate index) so after an 8-lane shfl_xor butterfly over
// k-chunks the lane owns i,f,g,o in registers, keeps c in a register, and
// publishes h immediately. 2 barriers/step, no LDS reduction scratch.
// Handshake: tagged 64-bit relaxed agent atomics, parity double-buffered.
__global__ __launch_bounds__(256, 1)
void lstm_kernel(const int* __restrict__ sent, const float* __restrict__ emb,
                 const float* __restrict__ W_ih, const float* __restrict__ W_hh,
                 const float* __restrict__ b_ih, const float* __restrict__ b_hh,
                 const float* __restrict__ W_z,
                 unsigned long long* __restrict__ hbuf,
                 float* __restrict__ part)
{
    __shared__ float x_sw[4 * XLD];
    __shared__ float h_sw[4 * XLD];
    __shared__ float p_s[64];       // b_loc*16 + jj
    __shared__ int   tok_ns[4];

    const int tid  = threadIdx.x;
    // XCD-clustering swizzle (heuristic): group's 16 WGs -> one XCD.
    const int xcd  = blockIdx.x & 7;
    const int slot = blockIdx.x >> 3;       // 0..31
    const int grp  = xcd * 2 + (slot >> 4); // 0..15 batch group
    const int jgrp = slot & 15;             // 0..15 j-slice
    const int b0   = grp << 2;
    const int j0   = jgrp << 4;

    const int wv    = tid >> 6;
    const int lane  = tid & 63;
    const int bp    = wv >> 1;              // batch pair 0..1
    const int jjhi  = wv & 1;
    const int jjlo  = lane >> 3;            // 0..7
    const int kc    = lane & 7;             // 0..7 k-chunk (32 floats)
    const int jj    = jjhi * 8 + jjlo;      // 0..15
    const int kbase = kc << 5;

    // ---- W chunks -> VGPRs (rows i*16+jj: all 4 gates of this jj) ----
    float4 wih_r[32], whh_r[32];
    float  bias_g[4];
    #pragma unroll
    for (int i = 0; i < 4; ++i) {
        long grow = (long)(i * HH + j0 + jj);
        const float4* wi = (const float4*)(W_ih + grow * EE + kbase);
        const float4* wh = (const float4*)(W_hh + grow * EE + kbase);
        #pragma unroll
        for (int mi = 0; mi < 8; ++mi) {
            wih_r[i * 8 + mi] = wi[mi];
            whh_r[i * 8 + mi] = wh[mi];
        }
        bias_g[i] = b_ih[grow] + b_hh[grow];
    }
    const float wz_r = W_z[j0 + jj];
    float c_r = 0.f;                        // cell state (owner lanes only)

    if (tid < 4) tok_ns[tid] = sent[0 * NB + b0 + tid];
    __syncthreads();
    {   // prologue: stage x for t=0 (swizzled)
        int b  = tid >> 6;
        int e4 = tid & 63;
        float4 xv = ((const float4*)(emb + (long)tok_ns[b] * EE))[e4];
        int phys = 4 * e4 + ((e4 >> 3) << 2);
        *(float4*)(&x_sw[b * XLD + phys]) = xv;
    }
    __syncthreads();

    // consumer fill mapping: this thread loads h[(b0+cb)][cj..cj+3]
    const int cb = tid >> 6;
    const int cj = (tid & 63) << 2;
    const int cphys = cj + ((cj >> 5) << 2);

    for (int t = 0; t < TT; ++t) {
        // ---- phase 1: x partials (x_sw staged previous iteration) ----
        float4 acc4[4][2];
        #pragma unroll
        for (int i = 0; i < 4; ++i)
            #pragma unroll
            for (int j = 0; j < 2; ++j)
                acc4[i][j] = make_float4(0.f, 0.f, 0.f, 0.f);

        #pragma unroll
        for (int j = 0; j < 2; ++j) {
            const float* xb = &x_sw[(2 * bp + j) * XLD + kc * 36];
            #pragma unroll
            for (int mi = 0; mi < 8; ++mi) {
                float4 xv4 = *(const float4*)(xb + mi * 4);
                #pragma unroll
                for (int i = 0; i < 4; ++i) {
                    float4 w = wih_r[i * 8 + mi];
                    acc4[i][j].x += w.x * xv4.x; acc4[i][j].y += w.y * xv4.y;
                    acc4[i][j].z += w.z * xv4.z; acc4[i][j].w += w.w * xv4.w;
                }
            }
        }

        const bool pf = (t + 1 < TT);
        if (tid < 4 && pf) tok_ns[tid] = sent[(t + 1) * NB + b0 + tid];

        // ---- phase 2a: direct tagged spin-load of h_{t-1} ----
        if (t > 0) {
            const unsigned want = (unsigned)t;   // h_{t-1} carries tag t
            unsigned long long* hp =
                hbuf + ((size_t)(((t - 1) & 1) * NB + b0 + cb)) * HH + cj;
            unsigned long long v0, v1, v2, v3;
            v0 = __hip_atomic_load(hp + 0, __ATOMIC_RELAXED, __HIP_MEMORY_SCOPE_AGENT);
            v1 = __hip_atomic_load(hp + 1, __ATOMIC_RELAXED, __HIP_MEMORY_SCOPE_AGENT);
            v2 = __hip_atomic_load(hp + 2, __ATOMIC_RELAXED, __HIP_MEMORY_SCOPE_AGENT);
            v3 = __hip_atomic_load(hp + 3, __ATOMIC_RELAXED, __HIP_MEMORY_SCOPE_AGENT);
            while ((unsigned)(v0 >> 32) != want)
                v0 = __hip_atomic_load(hp + 0, __ATOMIC_RELAXED, __HIP_MEMORY_SCOPE_AGENT);
            while ((unsigned)(v1 >> 32) != want)
                v1 = __hip_atomic_load(hp + 1, __ATOMIC_RELAXED, __HIP_MEMORY_SCOPE_AGENT);
            while ((unsigned)(v2 >> 32) != want)
                v2 = __hip_atomic_load(hp + 2, __ATOMIC_RELAXED, __HIP_MEMORY_SCOPE_AGENT);
            while ((unsigned)(v3 >> 32) != want)
                v3 = __hip_atomic_load(hp + 3, __ATOMIC_RELAXED, __HIP_MEMORY_SCOPE_AGENT);
            union { unsigned u; float f; } c0, c1, c2, c3;
            c0.u = (unsigned)v0; c1.u = (unsigned)v1;
            c2.u = (unsigned)v2; c3.u = (unsigned)v3;
            *(float4*)(&h_sw[cb * XLD + cphys]) =
                make_float4(c0.f, c1.f, c2.f, c3.f);
        }
        __syncthreads();   // B1: h_sw ready; x_sw reads done; tok_ns ready

        float4 xv;         // emb prefetch (completes behind hacc)
        if (pf) {
            int b  = tid >> 6;
            int e4 = tid & 63;
            xv = ((const float4*)(emb + (long)tok_ns[b] * EE))[e4];
        }

        // ---- phase 2b: h partials into same accumulators ----
        if (t > 0) {
            #pragma unroll
            for (int j = 0; j < 2; ++j) {
                const float* hb = &h_sw[(2 * bp + j) * XLD + kc * 36];
                #pragma unroll
                for (int mi = 0; mi < 8; ++mi) {
                    float4 hv4 = *(const float4*)(hb + mi * 4);
                    #pragma unroll
                    for (int i = 0; i < 4; ++i) {
                        float4 w = whh_r[i * 8 + mi];
                        acc4[i][j].x += w.x * hv4.x; acc4[i][j].y += w.y * hv4.y;
                        acc4[i][j].z += w.z * hv4.z; acc4[i][j].w += w.w * hv4.w;
                    }
                }
            }
        }

        // ---- phase 2c: horizontal add + 8-lane shfl butterfly over kc ----
        float sacc[8];
        #pragma unroll
        for (int i = 0; i < 4; ++i)
            #pragma unroll
            for (int j = 0; j < 2; ++j)
                sacc[i * 2 + j] = (acc4[i][j].x + acc4[i][j].y) +
                                  (acc4[i][j].z + acc4[i][j].w);
        #pragma unroll
        for (int a = 0; a < 8; ++a) sacc[a] += __shfl_xor(sacc[a], 1);
        #pragma unroll
        for (int a = 0; a < 8; ++a) sacc[a] += __shfl_xor(sacc[a], 2);
        #pragma unroll
        for (int a = 0; a < 8; ++a) sacc[a] += __shfl_xor(sacc[a], 4);
        // all 8 lanes of a (jj,bp) cluster now hold identical full sums

        // ---- phase 3: owner lanes (kc<2) do gates + publish, in-register ----
        if (kc < 2) {
            const int j  = kc;                 // batch within pair
            const int bl = bp * 2 + j;         // local batch 0..3
            float gi = bias_g[0] + sacc[0 + j];
            float gf = bias_g[1] + sacc[2 + j];
            float gg = bias_g[2] + sacc[4 + j];
            float go = bias_g[3] + sacc[6 + j];
            float cn = sigf(gf) * c_r + sigf(gi) * tanhf(gg);
            float hn = sigf(go) * tanhf(cn);
            c_r = cn;
            p_s[bl * 16 + jj] = hn * wz_r;
            __hip_atomic_store(
                hbuf + ((size_t)((t & 1) * NB + b0 + bl)) * HH + j0 + jj,
                packh((unsigned)(t + 1), hn),
                __ATOMIC_RELAXED, __HIP_MEMORY_SCOPE_AGENT);
        }

        if (pf) {          // stage next x (x_sw readers all finished pre-B1)
            int b  = tid >> 6;
            int e4 = tid & 63;
            int phys = 4 * e4 + ((e4 >> 3) << 2);
            *(float4*)(&x_sw[b * XLD + phys]) = xv;
        }
        __syncthreads();   // B2: p_s + x_sw ready

        if (tid < 4) {     // deterministic pz partial for this (t, jslice, b)
            float s = 0.f;
            #pragma unroll
            for (int jl = 0; jl < JW; ++jl) s += p_s[tid * 16 + jl];
            part[(t * PJ + jgrp) * NB + b0 + tid] = s;
        }
        // next p_s writes happen after next B1, which all threads (incl.
        // these readers) must pass first -> no race on p_s.
    }
}

__global__ void pz_kernel(const float* __restrict__ part,
                          const float* __restrict__ noise,
                          const float* __restrict__ b_z,
                          float* __restrict__ out)
{
    int idx = blockIdx.x * blockDim.x + threadIdx.x;  // t*64 + b
    if (idx >= TT * NB) return;
    int t = idx >> 6, b = idx & 63;
    float s = b_z[0];
    #pragma unroll
    for (int jg = 0; jg < PJ; ++jg) s += part[(t * PJ + jg) * NB + b];
    float pz = 1.f / (1.f + expf(-s));
    out[idx] = pz;
    out[TT * NB + idx] = (noise[idx] < pz) ? 1.f : 0.f;
}

// One block per batch column: stable compaction of tokens where z==1.
__global__ void compact_kernel(const int* __restrict__ sent,
                               const float* __restrict__ zbuf,
                               float* __restrict__ rat,
                               float* __restrict__ zsz)
{
    __shared__ float rat_s[TT];
    __shared__ int scan_s[256];
    int b = blockIdx.x, tid = threadIdx.x;
    int zloc[8];
    int base = tid * 8;
    int c = 0;
    #pragma unroll
    for (int i = 0; i < 8; ++i) {
        zloc[i] = (zbuf[(base + i) * NB + b] != 0.f) ? 1 : 0;
        c += zloc[i];
    }
    scan_s[tid] = c;
    for (int i = tid; i < TT; i += 256) rat_s[i] = 0.f;
    __syncthreads();
    for (int off = 1; off < 256; off <<= 1) {
        int v = scan_s[tid];
        int add = (tid >= off) ? scan_s[tid - off] : 0;
        __syncthreads();
        scan_s[tid] = v + add;
        __syncthreads();
    }
    int total = scan_s[255];
    int pos = scan_s[tid] - c;  // exclusive prefix
    #pragma unroll
    for (int i = 0; i < 8; ++i) {
        if (zloc[i]) { rat_s[pos] = (float)sent[(base + i) * NB + b]; ++pos; }
    }
    __syncthreads();
    for (int i = tid; i < TT; i += 256) rat[i * NB + b] = rat_s[i];
    if (tid == 0) zsz[b] = (float)total;
}

extern "C" void kernel_launch(void* const* d_in, const int* in_sizes, int n_in,
                              void* d_out, int out_size, void* d_ws, size_t ws_size,
                              hipStream_t stream)
{
    const int*   sent  = (const int*)d_in[0];
    const float* noise = (const float*)d_in[1];
    const float* emb   = (const float*)d_in[2];
    const float* W_ih  = (const float*)d_in[3];
    const float* W_hh  = (const float*)d_in[4];
    const float* b_ih  = (const float*)d_in[5];
    const float* b_hh  = (const float*)d_in[6];
    const float* W_z   = (const float*)d_in[7];
    const float* b_z   = (const float*)d_in[8];
    float* out = (float*)d_out;

    char* ws = (char*)d_ws;
    unsigned long long* hbuf = (unsigned long long*)ws;     // 2*64*256*8 = 256 KB
    float* part = (float*)(ws + 262144);                    // 2048*16*64*4 = 8 MB

    // tags must start != any expected tag (1..2048)
    hipMemsetAsync(hbuf, 0, 2 * NB * HH * sizeof(unsigned long long), stream);

    lstm_kernel<<<256, 256, 0, stream>>>(sent, emb, W_ih, W_hh, b_ih, b_hh, W_z,
                                         hbuf, part);
    pz_kernel<<<(TT * NB) / 256, 256, 0, stream>>>(part, noise, b_z, out);
    compact_kernel<<<NB, 256, 0, stream>>>(sent, out + TT * NB,
                                           out + 2 * TT * NB, out + 3 * TT * NB);
}

// Round 8
// 8361.111 us; speedup vs baseline: 5.0764x; 5.0764x over previous
//
#include <hip/hip_runtime.h>
#include <math.h>

#define TT 2048
#define NB 64
#define EE 256
#define HH 256
#define NGRP 16   // batch groups (4 batches each)
#define PJ 16     // j-partitions (WGs) per group
#define JW 16     // j per WG
#define XLD 288   // swizzled x/h row: phys(k) = k + (k>>5)*4 (chunk kc at kc*36)
// W_ih LDS layout: chunk-major [kc][row][36] -> flat (kc*64+row)*36 + mi*4
#define WIH(kc_, row_, mi_) (((kc_) * 64 + (row_)) * 36 + (mi_) * 4)

__device__ __forceinline__ float sigf(float x) { return 1.f / (1.f + expf(-x)); }

__device__ __forceinline__ unsigned long long packh(unsigned tag, float v) {
    union { float f; unsigned u; } c; c.f = v;
    return ((unsigned long long)tag << 32) | (unsigned long long)c.u;
}

// Persistent grouped LSTM: 256 WGs = 16 batch-groups x 16 j-slices, 1 WG/CU.
// R8 = R7 gate-colocated mapping (shfl-butterfly reduction, register c,
// immediate publish) with register pressure fixed: only W_hh in VGPRs
// (32 float4 = 128 regs); W_ih streams from LDS during xacc, which is off
// the critical path (overlapped with the publish->MALL flight).
// Handshake: tagged 64-bit relaxed agent atomics, parity double-buffered.
__global__ __launch_bounds__(256, 1)
void lstm_kernel(const int* __restrict__ sent, const float* __restrict__ emb,
                 const float* __restrict__ W_ih, const float* __restrict__ W_hh,
                 const float* __restrict__ b_ih, const float* __restrict__ b_hh,
                 const float* __restrict__ W_z,
                 unsigned long long* __restrict__ hbuf,
                 float* __restrict__ part)
{
    __shared__ float Wih_s[8 * 64 * 36];   // 73.7 KB, chunk-major (see WIH)
    __shared__ float x_sw[4 * XLD];
    __shared__ float h_sw[4 * XLD];
    __shared__ float p_s[64];              // b_loc*16 + jj
    __shared__ int   tok_ns[4];

    const int tid  = threadIdx.x;
    // XCD-clustering swizzle (heuristic): group's 16 WGs -> one XCD.
    const int xcd  = blockIdx.x & 7;
    const int slot = blockIdx.x >> 3;       // 0..31
    const int grp  = xcd * 2 + (slot >> 4); // 0..15 batch group
    const int jgrp = slot & 15;             // 0..15 j-slice
    const int b0   = grp << 2;
    const int j0   = jgrp << 4;

    const int wv    = tid >> 6;
    const int lane  = tid & 63;
    const int bp    = wv >> 1;              // batch pair 0..1
    const int jjhi  = wv & 1;
    const int jjlo  = lane >> 3;            // 0..7
    const int kc    = lane & 7;             // 0..7 k-chunk (32 floats)
    const int jj    = jjhi * 8 + jjlo;      // 0..15
    const int kbase = kc << 5;

    // ---- W_ih -> LDS (chunk-major), W_hh -> VGPRs ----
    for (int idx = tid; idx < 64 * 64; idx += 256) {
        int row = idx >> 6;                 // local row = gate*16 + jj
        int c4  = idx & 63;                 // float4 index within row
        long grow = (long)((row >> 4) * HH + j0 + (row & 15));
        float4 v = ((const float4*)(W_ih + grow * EE))[c4];
        *(float4*)(&Wih_s[WIH(c4 >> 3, row, c4 & 7)]) = v;
    }

    float4 whh_r[32];
    float  bias_g[4];
    #pragma unroll
    for (int i = 0; i < 4; ++i) {
        long grow = (long)(i * HH + j0 + jj);
        const float4* wh = (const float4*)(W_hh + grow * EE + kbase);
        #pragma unroll
        for (int mi = 0; mi < 8; ++mi) whh_r[i * 8 + mi] = wh[mi];
        bias_g[i] = b_ih[grow] + b_hh[grow];
    }
    const float wz_r = W_z[j0 + jj];
    float c_r = 0.f;                        // cell state (owner lanes only)

    if (tid < 4) tok_ns[tid] = sent[0 * NB + b0 + tid];
    __syncthreads();
    {   // prologue: stage x for t=0 (swizzled)
        int b  = tid >> 6;
        int e4 = tid & 63;
        float4 xv = ((const float4*)(emb + (long)tok_ns[b] * EE))[e4];
        int phys = 4 * e4 + ((e4 >> 3) << 2);
        *(float4*)(&x_sw[b * XLD + phys]) = xv;
    }
    __syncthreads();

    // consumer fill mapping: this thread loads h[(b0+cb)][cj..cj+3]
    const int cb = tid >> 6;
    const int cj = (tid & 63) << 2;
    const int cphys = cj + ((cj >> 5) << 2);

    for (int t = 0; t < TT; ++t) {
        // ---- phase 1: x partials (W_ih from LDS; hidden behind flight) ----
        float4 acc4[4][2];
        #pragma unroll
        for (int i = 0; i < 4; ++i)
            #pragma unroll
            for (int j = 0; j < 2; ++j)
                acc4[i][j] = make_float4(0.f, 0.f, 0.f, 0.f);

        {
            const float* xb0 = &x_sw[(2 * bp + 0) * XLD + kc * 36];
            const float* xb1 = &x_sw[(2 * bp + 1) * XLD + kc * 36];
            #pragma unroll
            for (int mi = 0; mi < 8; ++mi) {
                float4 x0 = *(const float4*)(xb0 + mi * 4);
                float4 x1 = *(const float4*)(xb1 + mi * 4);
                #pragma unroll
                for (int i = 0; i < 4; ++i) {
                    float4 w = *(const float4*)(&Wih_s[WIH(kc, i * 16 + jj, mi)]);
                    acc4[i][0].x += w.x * x0.x; acc4[i][0].y += w.y * x0.y;
                    acc4[i][0].z += w.z * x0.z; acc4[i][0].w += w.w * x0.w;
                    acc4[i][1].x += w.x * x1.x; acc4[i][1].y += w.y * x1.y;
                    acc4[i][1].z += w.z * x1.z; acc4[i][1].w += w.w * x1.w;
                }
            }
        }

        const bool pf = (t + 1 < TT);
        if (tid < 4 && pf) tok_ns[tid] = sent[(t + 1) * NB + b0 + tid];

        // ---- phase 2a: direct tagged spin-load of h_{t-1} ----
        if (t > 0) {
            const unsigned want = (unsigned)t;   // h_{t-1} carries tag t
            unsigned long long* hp =
                hbuf + ((size_t)(((t - 1) & 1) * NB + b0 + cb)) * HH + cj;
            unsigned long long v0, v1, v2, v3;
            v0 = __hip_atomic_load(hp + 0, __ATOMIC_RELAXED, __HIP_MEMORY_SCOPE_AGENT);
            v1 = __hip_atomic_load(hp + 1, __ATOMIC_RELAXED, __HIP_MEMORY_SCOPE_AGENT);
            v2 = __hip_atomic_load(hp + 2, __ATOMIC_RELAXED, __HIP_MEMORY_SCOPE_AGENT);
            v3 = __hip_atomic_load(hp + 3, __ATOMIC_RELAXED, __HIP_MEMORY_SCOPE_AGENT);
            while ((unsigned)(v0 >> 32) != want)
                v0 = __hip_atomic_load(hp + 0, __ATOMIC_RELAXED, __HIP_MEMORY_SCOPE_AGENT);
            while ((unsigned)(v1 >> 32) != want)
                v1 = __hip_atomic_load(hp + 1, __ATOMIC_RELAXED, __HIP_MEMORY_SCOPE_AGENT);
            while ((unsigned)(v2 >> 32) != want)
                v2 = __hip_atomic_load(hp + 2, __ATOMIC_RELAXED, __HIP_MEMORY_SCOPE_AGENT);
            while ((unsigned)(v3 >> 32) != want)
                v3 = __hip_atomic_load(hp + 3, __ATOMIC_RELAXED, __HIP_MEMORY_SCOPE_AGENT);
            union { unsigned u; float f; } c0, c1, c2, c3;
            c0.u = (unsigned)v0; c1.u = (unsigned)v1;
            c2.u = (unsigned)v2; c3.u = (unsigned)v3;
            *(float4*)(&h_sw[cb * XLD + cphys]) =
                make_float4(c0.f, c1.f, c2.f, c3.f);
        }
        __syncthreads();   // B1: h_sw ready; x_sw reads done; tok_ns ready

        float4 xv;         // emb prefetch (completes behind hacc)
        if (pf) {
            int b  = tid >> 6;
            int e4 = tid & 63;
            xv = ((const float4*)(emb + (long)tok_ns[b] * EE))[e4];
        }

        // ---- phase 2b: h partials, register-fed W_hh (critical path) ----
        if (t > 0) {
            const float* hb0 = &h_sw[(2 * bp + 0) * XLD + kc * 36];
            const float* hb1 = &h_sw[(2 * bp + 1) * XLD + kc * 36];
            #pragma unroll
            for (int mi = 0; mi < 8; ++mi) {
                float4 h0 = *(const float4*)(hb0 + mi * 4);
                float4 h1 = *(const float4*)(hb1 + mi * 4);
                #pragma unroll
                for (int i = 0; i < 4; ++i) {
                    float4 w = whh_r[i * 8 + mi];
                    acc4[i][0].x += w.x * h0.x; acc4[i][0].y += w.y * h0.y;
                    acc4[i][0].z += w.z * h0.z; acc4[i][0].w += w.w * h0.w;
                    acc4[i][1].x += w.x * h1.x; acc4[i][1].y += w.y * h1.y;
                    acc4[i][1].z += w.z * h1.z; acc4[i][1].w += w.w * h1.w;
                }
            }
        }

        // ---- phase 2c: horizontal add + 8-lane shfl butterfly over kc ----
        float sacc[8];
        #pragma unroll
        for (int i = 0; i < 4; ++i)
            #pragma unroll
            for (int j = 0; j < 2; ++j)
                sacc[i * 2 + j] = (acc4[i][j].x + acc4[i][j].y) +
                                  (acc4[i][j].z + acc4[i][j].w);
        #pragma unroll
        for (int a = 0; a < 8; ++a) sacc[a] += __shfl_xor(sacc[a], 1);
        #pragma unroll
        for (int a = 0; a < 8; ++a) sacc[a] += __shfl_xor(sacc[a], 2);
        #pragma unroll
        for (int a = 0; a < 8; ++a) sacc[a] += __shfl_xor(sacc[a], 4);
        // all 8 lanes of a (jj,bp) cluster now hold identical full sums

        // ---- phase 3: owner lanes (kc<2) gates + publish, in-register ----
        if (kc < 2) {
            const int j  = kc;                 // batch within pair
            const int bl = bp * 2 + j;         // local batch 0..3
            float gi = bias_g[0] + sacc[0 + j];
            float gf = bias_g[1] + sacc[2 + j];
            float gg = bias_g[2] + sacc[4 + j];
            float go = bias_g[3] + sacc[6 + j];
            float cn = sigf(gf) * c_r + sigf(gi) * tanhf(gg);
            float hn = sigf(go) * tanhf(cn);
            c_r = cn;
            p_s[bl * 16 + jj] = hn * wz_r;
            __hip_atomic_store(
                hbuf + ((size_t)((t & 1) * NB + b0 + bl)) * HH + j0 + jj,
                packh((unsigned)(t + 1), hn),
                __ATOMIC_RELAXED, __HIP_MEMORY_SCOPE_AGENT);
        }

        if (pf) {          // stage next x (x_sw readers all finished pre-B1)
            int b  = tid >> 6;
            int e4 = tid & 63;
            int phys = 4 * e4 + ((e4 >> 3) << 2);
            *(float4*)(&x_sw[b * XLD + phys]) = xv;
        }
        __syncthreads();   // B2: p_s + x_sw ready

        if (tid < 4) {     // deterministic pz partial for this (t, jslice, b)
            float s = 0.f;
            #pragma unroll
            for (int jl = 0; jl < JW; ++jl) s += p_s[tid * 16 + jl];
            part[(t * PJ + jgrp) * NB + b0 + tid] = s;
        }
        // p_s next written only after next B1, which these readers gate.
    }
}

__global__ void pz_kernel(const float* __restrict__ part,
                          const float* __restrict__ noise,
                          const float* __restrict__ b_z,
                          float* __restrict__ out)
{
    int idx = blockIdx.x * blockDim.x + threadIdx.x;  // t*64 + b
    if (idx >= TT * NB) return;
    int t = idx >> 6, b = idx & 63;
    float s = b_z[0];
    #pragma unroll
    for (int jg = 0; jg < PJ; ++jg) s += part[(t * PJ + jg) * NB + b];
    float pz = 1.f / (1.f + expf(-s));
    out[idx] = pz;
    out[TT * NB + idx] = (noise[idx] < pz) ? 1.f : 0.f;
}

// One block per batch column: stable compaction of tokens where z==1.
__global__ void compact_kernel(const int* __restrict__ sent,
                               const float* __restrict__ zbuf,
                               float* __restrict__ rat,
                               float* __restrict__ zsz)
{
    __shared__ float rat_s[TT];
    __shared__ int scan_s[256];
    int b = blockIdx.x, tid = threadIdx.x;
    int zloc[8];
    int base = tid * 8;
    int c = 0;
    #pragma unroll
    for (int i = 0; i < 8; ++i) {
        zloc[i] = (zbuf[(base + i) * NB + b] != 0.f) ? 1 : 0;
        c += zloc[i];
    }
    scan_s[tid] = c;
    for (int i = tid; i < TT; i += 256) rat_s[i] = 0.f;
    __syncthreads();
    for (int off = 1; off < 256; off <<= 1) {
        int v = scan_s[tid];
        int add = (tid >= off) ? scan_s[tid - off] : 0;
        __syncthreads();
        scan_s[tid] = v + add;
        __syncthreads();
    }
    int total = scan_s[255];
    int pos = scan_s[tid] - c;  // exclusive prefix
    #pragma unroll
    for (int i = 0; i < 8; ++i) {
        if (zloc[i]) { rat_s[pos] = (float)sent[(base + i) * NB + b]; ++pos; }
    }
    __syncthreads();
    for (int i = tid; i < TT; i += 256) rat[i * NB + b] = rat_s[i];
    if (tid == 0) zsz[b] = (float)total;
}

extern "C" void kernel_launch(void* const* d_in, const int* in_sizes, int n_in,
                              void* d_out, int out_size, void* d_ws, size_t ws_size,
                              hipStream_t stream)
{
    const int*   sent  = (const int*)d_in[0];
    const float* noise = (const float*)d_in[1];
    const float* emb   = (const float*)d_in[2];
    const float* W_ih  = (const float*)d_in[3];
    const float* W_hh  = (const float*)d_in[4];
    const float* b_ih  = (const float*)d_in[5];
    const float* b_hh  = (const float*)d_in[6];
    const float* W_z   = (const float*)d_in[7];
    const float* b_z   = (const float*)d_in[8];
    float* out = (float*)d_out;

    char* ws = (char*)d_ws;
    unsigned long long* hbuf = (unsigned long long*)ws;     // 2*64*256*8 = 256 KB
    float* part = (float*)(ws + 262144);                    // 2048*16*64*4 = 8 MB

    // tags must start != any expected tag (1..2048)
    hipMemsetAsync(hbuf, 0, 2 * NB * HH * sizeof(unsigned long long), stream);

    lstm_kernel<<<256, 256, 0, stream>>>(sent, emb, W_ih, W_hh, b_ih, b_hh, W_z,
                                         hbuf, part);
    pz_kernel<<<(TT * NB) / 256, 256, 0, stream>>>(part, noise, b_z, out);
    compact_kernel<<<NB, 256, 0, stream>>>(sent, out + TT * NB,
                                           out + 2 * TT * NB, out + 3 * TT * NB);
}

// Round 9
// 7879.476 us; speedup vs baseline: 5.3867x; 1.0611x over previous
//
#include <hip/hip_runtime.h>
#include <math.h>

#define TT 2048
#define NB 64
#define EE 256
#define HH 256
#define NGRP 16   // batch groups (4 batches each)
#define PJ 16     // j-partitions (WGs) per group
#define JW 16     // j per WG
#define XLD 320   // swizzled x/h row: phys(k) = k + ((k>>4)<<2); chunk kc at kc*20

__device__ __forceinline__ float sigf(float x) { return 1.f / (1.f + expf(-x)); }

__device__ __forceinline__ unsigned long long packh(unsigned tag, float v) {
    union { float f; unsigned u; } c; c.f = v;
    return ((unsigned long long)tag << 32) | (unsigned long long)c.u;
}

// Persistent grouped LSTM: 256 WGs = 16 batch-groups x 16 j-slices, 1 WG/CU.
// R9: gate-colocated, ALL weights in registers, 16-float k-chunks.
// Thread = (jj 0..15 [wv*4+jjlo], kc 0..15); owns rows i*16+jj (i=gate) over
// chunk [kc*16,kc*16+16) for all 4 batches. W regs: 32 float4 (128 VGPR).
// LDS per step: 16 x + 16 h b128 broadcasts (2-way max, swizzled stride 20).
// Reduction: 4-stage 16-lane shfl_xor butterfly; owner lanes (kc<4, batch=kc)
// keep c in-register, publish tagged 64-bit relaxed agent atomics (parity
// double-buffered). 2 barriers/step.
__global__ __launch_bounds__(256, 1)
void lstm_kernel(const int* __restrict__ sent, const float* __restrict__ emb,
                 const float* __restrict__ W_ih, const float* __restrict__ W_hh,
                 const float* __restrict__ b_ih, const float* __restrict__ b_hh,
                 const float* __restrict__ W_z,
                 unsigned long long* __restrict__ hbuf,
                 float* __restrict__ part)
{
    __shared__ float x_sw[4 * XLD];
    __shared__ float h_sw[4 * XLD];
    __shared__ float p_s[64];              // b_loc*16 + jj
    __shared__ int   tok_ns[4];

    const int tid  = threadIdx.x;
    // XCD-clustering swizzle (heuristic): group's 16 WGs -> one XCD.
    const int xcd  = blockIdx.x & 7;
    const int slot = blockIdx.x >> 3;       // 0..31
    const int grp  = xcd * 2 + (slot >> 4); // 0..15 batch group
    const int jgrp = slot & 15;             // 0..15 j-slice
    const int b0   = grp << 2;
    const int j0   = jgrp << 4;

    const int wv    = tid >> 6;             // 0..3
    const int lane  = tid & 63;
    const int jjlo  = lane >> 4;            // 0..3
    const int kc    = lane & 15;            // 0..15 k-chunk (16 floats)
    const int jj    = wv * 4 + jjlo;        // 0..15
    const int kbase = kc << 4;

    // ---- all weights -> VGPRs: rows i*16+jj, 4 float4 per row per matrix ----
    float4 wih_r[16], whh_r[16];
    float  bias_g[4];
    #pragma unroll
    for (int i = 0; i < 4; ++i) {
        long grow = (long)(i * HH + j0 + jj);
        const float4* wi = (const float4*)(W_ih + grow * EE + kbase);
        const float4* wh = (const float4*)(W_hh + grow * EE + kbase);
        #pragma unroll
        for (int mi = 0; mi < 4; ++mi) {
            wih_r[i * 4 + mi] = wi[mi];
            whh_r[i * 4 + mi] = wh[mi];
        }
        bias_g[i] = b_ih[grow] + b_hh[grow];
    }
    const float wz_r = W_z[j0 + jj];
    float c_r = 0.f;                        // cell state (owner lanes only)

    if (tid < 4) tok_ns[tid] = sent[0 * NB + b0 + tid];
    __syncthreads();
    {   // prologue: stage x for t=0 (swizzled: phys(k)=k+((k>>4)<<2))
        int b  = tid >> 6;
        int e4 = tid & 63;
        float4 xv = ((const float4*)(emb + (long)tok_ns[b] * EE))[e4];
        int k = 4 * e4;
        int phys = k + ((k >> 4) << 2);
        *(float4*)(&x_sw[b * XLD + phys]) = xv;
    }
    __syncthreads();

    // consumer fill mapping: this thread loads h[(b0+cb)][cj..cj+3]
    const int cb = tid >> 6;
    const int cj = (tid & 63) << 2;
    const int cphys = cj + ((cj >> 4) << 2);

    for (int t = 0; t < TT; ++t) {
        // ---- phase 1: x partials (register W_ih; overlaps publish flight) ----
        float4 acc4[16];                    // index i*4 + b
        #pragma unroll
        for (int a = 0; a < 16; ++a) acc4[a] = make_float4(0.f, 0.f, 0.f, 0.f);

        #pragma unroll
        for (int b = 0; b < 4; ++b) {
            const float* xb = &x_sw[b * XLD + kc * 20];
            #pragma unroll
            for (int mi = 0; mi < 4; ++mi) {
                float4 xv4 = *(const float4*)(xb + mi * 4);
                #pragma unroll
                for (int i = 0; i < 4; ++i) {
                    float4 w = wih_r[i * 4 + mi];
                    acc4[i * 4 + b].x += w.x * xv4.x;
                    acc4[i * 4 + b].y += w.y * xv4.y;
                    acc4[i * 4 + b].z += w.z * xv4.z;
                    acc4[i * 4 + b].w += w.w * xv4.w;
                }
            }
        }

        const bool pf = (t + 1 < TT);
        if (tid < 4 && pf) tok_ns[tid] = sent[(t + 1) * NB + b0 + tid];

        // ---- phase 2a: direct tagged spin-load of h_{t-1} ----
        if (t > 0) {
            const unsigned want = (unsigned)t;   // h_{t-1} carries tag t
            unsigned long long* hp =
                hbuf + ((size_t)(((t - 1) & 1) * NB + b0 + cb)) * HH + cj;
            unsigned long long v0, v1, v2, v3;
            v0 = __hip_atomic_load(hp + 0, __ATOMIC_RELAXED, __HIP_MEMORY_SCOPE_AGENT);
            v1 = __hip_atomic_load(hp + 1, __ATOMIC_RELAXED, __HIP_MEMORY_SCOPE_AGENT);
            v2 = __hip_atomic_load(hp + 2, __ATOMIC_RELAXED, __HIP_MEMORY_SCOPE_AGENT);
            v3 = __hip_atomic_load(hp + 3, __ATOMIC_RELAXED, __HIP_MEMORY_SCOPE_AGENT);
            while ((unsigned)(v0 >> 32) != want)
                v0 = __hip_atomic_load(hp + 0, __ATOMIC_RELAXED, __HIP_MEMORY_SCOPE_AGENT);
            while ((unsigned)(v1 >> 32) != want)
                v1 = __hip_atomic_load(hp + 1, __ATOMIC_RELAXED, __HIP_MEMORY_SCOPE_AGENT);
            while ((unsigned)(v2 >> 32) != want)
                v2 = __hip_atomic_load(hp + 2, __ATOMIC_RELAXED, __HIP_MEMORY_SCOPE_AGENT);
            while ((unsigned)(v3 >> 32) != want)
                v3 = __hip_atomic_load(hp + 3, __ATOMIC_RELAXED, __HIP_MEMORY_SCOPE_AGENT);
            union { unsigned u; float f; } c0, c1, c2, c3;
            c0.u = (unsigned)v0; c1.u = (unsigned)v1;
            c2.u = (unsigned)v2; c3.u = (unsigned)v3;
            *(float4*)(&h_sw[cb * XLD + cphys]) =
                make_float4(c0.f, c1.f, c2.f, c3.f);
        }
        __syncthreads();   // B1: h_sw ready; x_sw reads done; tok_ns ready

        float4 xv;         // emb prefetch (completes behind hacc)
        if (pf) {
            int b  = tid >> 6;
            int e4 = tid & 63;
            xv = ((const float4*)(emb + (long)tok_ns[b] * EE))[e4];
        }

        // ---- phase 2b: h partials, register W_hh (critical path) ----
        if (t > 0) {
            #pragma unroll
            for (int b = 0; b < 4; ++b) {
                const float* hb = &h_sw[b * XLD + kc * 20];
                #pragma unroll
                for (int mi = 0; mi < 4; ++mi) {
                    float4 hv4 = *(const float4*)(hb + mi * 4);
                    #pragma unroll
                    for (int i = 0; i < 4; ++i) {
                        float4 w = whh_r[i * 4 + mi];
                        acc4[i * 4 + b].x += w.x * hv4.x;
                        acc4[i * 4 + b].y += w.y * hv4.y;
                        acc4[i * 4 + b].z += w.z * hv4.z;
                        acc4[i * 4 + b].w += w.w * hv4.w;
                    }
                }
            }
        }

        // ---- phase 2c: horizontal add + 16-lane shfl butterfly over kc ----
        float sacc[16];
        #pragma unroll
        for (int a = 0; a < 16; ++a)
            sacc[a] = (acc4[a].x + acc4[a].y) + (acc4[a].z + acc4[a].w);
        #pragma unroll
        for (int a = 0; a < 16; ++a) sacc[a] += __shfl_xor(sacc[a], 1);
        #pragma unroll
        for (int a = 0; a < 16; ++a) sacc[a] += __shfl_xor(sacc[a], 2);
        #pragma unroll
        for (int a = 0; a < 16; ++a) sacc[a] += __shfl_xor(sacc[a], 4);
        #pragma unroll
        for (int a = 0; a < 16; ++a) sacc[a] += __shfl_xor(sacc[a], 8);
        // all 16 lanes of a jj-cluster now hold the full sums

        // ---- phase 3: owner lanes (kc<4, batch=kc) gates + publish ----
        if (kc < 4) {
            const int bl = kc;                 // local batch 0..3
            float gi = bias_g[0] + sacc[0 * 4 + bl];
            float gf = bias_g[1] + sacc[1 * 4 + bl];
            float gg = bias_g[2] + sacc[2 * 4 + bl];
            float go = bias_g[3] + sacc[3 * 4 + bl];
            float cn = sigf(gf) * c_r + sigf(gi) * tanhf(gg);
            float hn = sigf(go) * tanhf(cn);
            c_r = cn;
            p_s[bl * 16 + jj] = hn * wz_r;
            __hip_atomic_store(
                hbuf + ((size_t)((t & 1) * NB + b0 + bl)) * HH + j0 + jj,
                packh((unsigned)(t + 1), hn),
                __ATOMIC_RELAXED, __HIP_MEMORY_SCOPE_AGENT);
        }

        if (pf) {          // stage next x (x_sw readers all finished pre-B1)
            int b  = tid >> 6;
            int e4 = tid & 63;
            int k = 4 * e4;
            int phys = k + ((k >> 4) << 2);
            *(float4*)(&x_sw[b * XLD + phys]) = xv;
        }
        __syncthreads();   // B2: p_s + x_sw ready

        if (tid < 4) {     // deterministic pz partial for this (t, jslice, b)
            float s = 0.f;
            #pragma unroll
            for (int jl = 0; jl < JW; ++jl) s += p_s[tid * 16 + jl];
            part[(t * PJ + jgrp) * NB + b0 + tid] = s;
        }
        // p_s next written only after next B1, which these readers gate.
    }
}

__global__ void pz_kernel(const float* __restrict__ part,
                          const float* __restrict__ noise,
                          const float* __restrict__ b_z,
                          float* __restrict__ out)
{
    int idx = blockIdx.x * blockDim.x + threadIdx.x;  // t*64 + b
    if (idx >= TT * NB) return;
    int t = idx >> 6, b = idx & 63;
    float s = b_z[0];
    #pragma unroll
    for (int jg = 0; jg < PJ; ++jg) s += part[(t * PJ + jg) * NB + b];
    float pz = 1.f / (1.f + expf(-s));
    out[idx] = pz;
    out[TT * NB + idx] = (noise[idx] < pz) ? 1.f : 0.f;
}

// One block per batch column: stable compaction of tokens where z==1.
__global__ void compact_kernel(const int* __restrict__ sent,
                               const float* __restrict__ zbuf,
                               float* __restrict__ rat,
                               float* __restrict__ zsz)
{
    __shared__ float rat_s[TT];
    __shared__ int scan_s[256];
    int b = blockIdx.x, tid = threadIdx.x;
    int zloc[8];
    int base = tid * 8;
    int c = 0;
    #pragma unroll
    for (int i = 0; i < 8; ++i) {
        zloc[i] = (zbuf[(base + i) * NB + b] != 0.f) ? 1 : 0;
        c += zloc[i];
    }
    scan_s[tid] = c;
    for (int i = tid; i < TT; i += 256) rat_s[i] = 0.f;
    __syncthreads();
    for (int off = 1; off < 256; off <<= 1) {
        int v = scan_s[tid];
        int add = (tid >= off) ? scan_s[tid - off] : 0;
        __syncthreads();
        scan_s[tid] = v + add;
        __syncthreads();
    }
    int total = scan_s[255];
    int pos = scan_s[tid] - c;  // exclusive prefix
    #pragma unroll
    for (int i = 0; i < 8; ++i) {
        if (zloc[i]) { rat_s[pos] = (float)sent[(base + i) * NB + b]; ++pos; }
    }
    __syncthreads();
    for (int i = tid; i < TT; i += 256) rat[i * NB + b] = rat_s[i];
    if (tid == 0) zsz[b] = (float)total;
}

extern "C" void kernel_launch(void* const* d_in, const int* in_sizes, int n_in,
                              void* d_out, int out_size, void* d_ws, size_t ws_size,
                              hipStream_t stream)
{
    const int*   sent  = (const int*)d_in[0];
    const float* noise = (const float*)d_in[1];
    const float* emb   = (const float*)d_in[2];
    const float* W_ih  = (const float*)d_in[3];
    const float* W_hh  = (const float*)d_in[4];
    const float* b_ih  = (const float*)d_in[5];
    const float* b_hh  = (const float*)d_in[6];
    const float* W_z   = (const float*)d_in[7];
    const float* b_z   = (const float*)d_in[8];
    float* out = (float*)d_out;

    char* ws = (char*)d_ws;
    unsigned long long* hbuf = (unsigned long long*)ws;     // 2*64*256*8 = 256 KB
    float* part = (float*)(ws + 262144);                    // 2048*16*64*4 = 8 MB

    // tags must start != any expected tag (1..2048)
    hipMemsetAsync(hbuf, 0, 2 * NB * HH * sizeof(unsigned long long), stream);

    lstm_kernel<<<256, 256, 0, stream>>>(sent, emb, W_ih, W_hh, b_ih, b_hh, W_z,
                                         hbuf, part);
    pz_kernel<<<(TT * NB) / 256, 256, 0, stream>>>(part, noise, b_z, out);
    compact_kernel<<<NB, 256, 0, stream>>>(sent, out + TT * NB,
                                           out + 2 * TT * NB, out + 3 * TT * NB);
}

// Round 10
// 7002.944 us; speedup vs baseline: 6.0609x; 1.1252x over previous
//
#include <hip/hip_runtime.h>
#include <math.h>

#define TT 2048
#define NB 64
#define EE 256
#define HH 256
#define NGRP 16   // batch groups (4 batches each)
#define PJ 16     // j-partitions (WGs) per group
#define JW 16     // j per WG
#define XLD 288   // swizzled x/h row: 32-float chunk kc at kc*36 (4 pad/chunk)
#define RST 288   // red_s kc stride in floats (batch stride 72, row stride 1)

__device__ __forceinline__ float sigf(float x) { return 1.f / (1.f + expf(-x)); }

__device__ __forceinline__ unsigned long long packh(unsigned tag, float v) {
    union { float f; unsigned u; } c; c.f = v;
    return ((unsigned long long)tag << 32) | (unsigned long long)c.u;
}

// Persistent grouped LSTM: 256 WGs = 16 batch-groups x 16 j-slices, 1 WG/CU.
// R10 = R6 (best known: W in regs/AGPRs, 32-float chunks, red_s partials)
// with the reduction tail merged into wave 0: reducer lane (b,jj) reads its
// 32 partials, computes all 4 gate pre-acts bit-identically to R6, keeps c
// in a register, publishes immediately; pz partial via order-preserving
// 16-shfl chain on the same wave. 2 barriers/step (was 4). red_s recycle is
// guarded by B1 of the next step (waves can't write red_s(t+1) before it).
__global__ __launch_bounds__(256, 1)
void lstm_kernel(const int* __restrict__ sent, const float* __restrict__ emb,
                 const float* __restrict__ W_ih, const float* __restrict__ W_hh,
                 const float* __restrict__ b_ih, const float* __restrict__ b_hh,
                 const float* __restrict__ W_z,
                 unsigned long long* __restrict__ hbuf,
                 float* __restrict__ part)
{
    __shared__ float x_sw[4 * XLD];
    __shared__ float h_sw[4 * XLD];
    __shared__ float red_s[8 * RST];   // [kc]*288 + [b]*72 + [row 0..63]
    __shared__ int   tok_ns[4];

    const int tid  = threadIdx.x;
    // XCD-clustering swizzle (heuristic): group's 16 WGs -> one XCD.
    const int xcd  = blockIdx.x & 7;
    const int slot = blockIdx.x >> 3;       // 0..31
    const int grp  = xcd * 2 + (slot >> 4); // 0..15 batch group
    const int jgrp = slot & 15;             // 0..15 j-slice
    const int b0   = grp << 2;
    const int j0   = jgrp << 4;

    const int wv    = tid >> 6;
    const int lane  = tid & 63;
    const int rg    = lane >> 2;            // 0..15 row-group (rows rg*4..+3)
    const int klow  = lane & 3;
    const int kc    = (wv >> 1) * 4 + klow; // 0..7  k-chunk (32 floats)
    const int bp    = wv & 1;               // batch pair
    const int kbase = kc << 5;

    // ---- weights -> VGPR/AGPR: rows rg*4+i over this thread's 32-chunk ----
    float4 wih_r[32], whh_r[32];
    #pragma unroll
    for (int i = 0; i < 4; ++i) {
        int lr_i = rg * 4 + i;
        long grow = (long)((lr_i >> 4) * HH + j0 + (lr_i & 15));
        const float4* wi = (const float4*)(W_ih + grow * EE + kbase);
        const float4* wh = (const float4*)(W_hh + grow * EE + kbase);
        #pragma unroll
        for (int mi = 0; mi < 8; ++mi) {
            wih_r[i * 8 + mi] = wi[mi];
            whh_r[i * 8 + mi] = wh[mi];
        }
    }

    // epilogue identity (wave 0 only uses these): lane = b_e*16 + jj_e
    const int jj_e = tid & 15;
    const int b_e  = (tid >> 4) & 3;
    float bias_g[4];
    #pragma unroll
    for (int i = 0; i < 4; ++i) {
        long grow = (long)(i * HH + j0 + jj_e);
        bias_g[i] = b_ih[grow] + b_hh[grow];
    }
    const float wz_r = W_z[j0 + jj_e];
    float c_r = 0.f;                        // cell state (wave-0 lanes)

    if (tid < 4) tok_ns[tid] = sent[0 * NB + b0 + tid];
    __syncthreads();
    {   // prologue: stage x for t=0 (swizzled)
        int b  = tid >> 6;
        int e4 = tid & 63;
        float4 xv = ((const float4*)(emb + (long)tok_ns[b] * EE))[e4];
        int phys = 4 * e4 + ((e4 >> 3) << 2);
        *(float4*)(&x_sw[b * XLD + phys]) = xv;
    }
    __syncthreads();

    // consumer fill mapping: this thread loads h[(b0+cb)][cj..cj+3]
    const int cb = tid >> 6;
    const int cj = (tid & 63) << 2;
    const int cphys = cj + ((cj >> 5) << 2);

    for (int t = 0; t < TT; ++t) {
        // ---- phase 1: x partials (overlaps publish->observe flight) ----
        float4 acc4[4][2];
        #pragma unroll
        for (int i = 0; i < 4; ++i)
            #pragma unroll
            for (int j = 0; j < 2; ++j)
                acc4[i][j] = make_float4(0.f, 0.f, 0.f, 0.f);

        {
            const float* xb0 = &x_sw[(2 * bp + 0) * XLD + kc * 36];
            const float* xb1 = &x_sw[(2 * bp + 1) * XLD + kc * 36];
            #pragma unroll
            for (int mi = 0; mi < 8; ++mi) {
                float4 x0 = *(const float4*)(xb0 + mi * 4);
                float4 x1 = *(const float4*)(xb1 + mi * 4);
                #pragma unroll
                for (int i = 0; i < 4; ++i) {
                    float4 w = wih_r[i * 8 + mi];
                    acc4[i][0].x += w.x * x0.x; acc4[i][0].y += w.y * x0.y;
                    acc4[i][0].z += w.z * x0.z; acc4[i][0].w += w.w * x0.w;
                    acc4[i][1].x += w.x * x1.x; acc4[i][1].y += w.y * x1.y;
                    acc4[i][1].z += w.z * x1.z; acc4[i][1].w += w.w * x1.w;
                }
            }
        }

        const bool pf = (t + 1 < TT);
        if (tid < 4 && pf) tok_ns[tid] = sent[(t + 1) * NB + b0 + tid];

        // ---- phase 2a: direct tagged spin-load of h_{t-1} ----
        if (t > 0) {
            const unsigned want = (unsigned)t;   // h_{t-1} carries tag t
            unsigned long long* hp =
                hbuf + ((size_t)(((t - 1) & 1) * NB + b0 + cb)) * HH + cj;
            unsigned long long v0, v1, v2, v3;
            v0 = __hip_atomic_load(hp + 0, __ATOMIC_RELAXED, __HIP_MEMORY_SCOPE_AGENT);
            v1 = __hip_atomic_load(hp + 1, __ATOMIC_RELAXED, __HIP_MEMORY_SCOPE_AGENT);
            v2 = __hip_atomic_load(hp + 2, __ATOMIC_RELAXED, __HIP_MEMORY_SCOPE_AGENT);
            v3 = __hip_atomic_load(hp + 3, __ATOMIC_RELAXED, __HIP_MEMORY_SCOPE_AGENT);
            while ((unsigned)(v0 >> 32) != want)
                v0 = __hip_atomic_load(hp + 0, __ATOMIC_RELAXED, __HIP_MEMORY_SCOPE_AGENT);
            while ((unsigned)(v1 >> 32) != want)
                v1 = __hip_atomic_load(hp + 1, __ATOMIC_RELAXED, __HIP_MEMORY_SCOPE_AGENT);
            while ((unsigned)(v2 >> 32) != want)
                v2 = __hip_atomic_load(hp + 2, __ATOMIC_RELAXED, __HIP_MEMORY_SCOPE_AGENT);
            while ((unsigned)(v3 >> 32) != want)
                v3 = __hip_atomic_load(hp + 3, __ATOMIC_RELAXED, __HIP_MEMORY_SCOPE_AGENT);
            union { unsigned u; float f; } c0, c1, c2, c3;
            c0.u = (unsigned)v0; c1.u = (unsigned)v1;
            c2.u = (unsigned)v2; c3.u = (unsigned)v3;
            *(float4*)(&h_sw[cb * XLD + cphys]) =
                make_float4(c0.f, c1.f, c2.f, c3.f);
        }
        __syncthreads();   // B1: h_sw ready; x_sw/red_s reads done; tok_ns ready

        float4 xv;         // emb prefetch (completes behind hacc)
        if (pf) {
            int b  = tid >> 6;
            int e4 = tid & 63;
            xv = ((const float4*)(emb + (long)tok_ns[b] * EE))[e4];
        }

        // ---- phase 2b: h partials (register W_hh; critical path) ----
        if (t > 0) {
            const float* hb0 = &h_sw[(2 * bp + 0) * XLD + kc * 36];
            const float* hb1 = &h_sw[(2 * bp + 1) * XLD + kc * 36];
            #pragma unroll
            for (int mi = 0; mi < 8; ++mi) {
                float4 h0 = *(const float4*)(hb0 + mi * 4);
                float4 h1 = *(const float4*)(hb1 + mi * 4);
                #pragma unroll
                for (int i = 0; i < 4; ++i) {
                    float4 w = whh_r[i * 8 + mi];
                    acc4[i][0].x += w.x * h0.x; acc4[i][0].y += w.y * h0.y;
                    acc4[i][0].z += w.z * h0.z; acc4[i][0].w += w.w * h0.w;
                    acc4[i][1].x += w.x * h1.x; acc4[i][1].y += w.y * h1.y;
                    acc4[i][1].z += w.z * h1.z; acc4[i][1].w += w.w * h1.w;
                }
            }
        }

        // horizontal-add partials, write to reduction scratch
        #pragma unroll
        for (int j = 0; j < 2; ++j) {
            int b = 2 * bp + j;
            float4 v;
            v.x = (acc4[0][j].x + acc4[0][j].y) + (acc4[0][j].z + acc4[0][j].w);
            v.y = (acc4[1][j].x + acc4[1][j].y) + (acc4[1][j].z + acc4[1][j].w);
            v.z = (acc4[2][j].x + acc4[2][j].y) + (acc4[2][j].z + acc4[2][j].w);
            v.w = (acc4[3][j].x + acc4[3][j].y) + (acc4[3][j].z + acc4[3][j].w);
            *(float4*)(&red_s[kc * RST + b * 72 + rg * 4]) = v;
        }
        if (pf) {          // stage next x (x_sw readers finished pre-B1)
            int b  = tid >> 6;
            int e4 = tid & 63;
            int phys = 4 * e4 + ((e4 >> 3) << 2);
            *(float4*)(&x_sw[b * XLD + phys]) = xv;
        }
        __syncthreads();   // B2: red_s + x_sw ready

        // ---- epilogue (wave 0 only): reduce + gates + publish + pz ----
        if (tid < 64) {
            float s[4];
            #pragma unroll
            for (int i = 0; i < 4; ++i) s[i] = bias_g[i];
            #pragma unroll
            for (int k2 = 0; k2 < 8; ++k2) {
                const float* rp = &red_s[k2 * RST + b_e * 72 + jj_e];
                #pragma unroll
                for (int i = 0; i < 4; ++i) s[i] += rp[i * 16];
            }
            float cn = sigf(s[1]) * c_r + sigf(s[0]) * tanhf(s[2]);
            float hn = sigf(s[3]) * tanhf(cn);
            c_r = cn;
            __hip_atomic_store(
                hbuf + ((size_t)((t & 1) * NB + b0 + b_e)) * HH + j0 + jj_e,
                packh((unsigned)(t + 1), hn),
                __ATOMIC_RELAXED, __HIP_MEMORY_SCOPE_AGENT);
            // order-preserving pz partial: sum p over jj ascending via shfl
            float p = hn * wz_r;
            float acc = 0.f;
            const int cbase = tid & 48;     // cluster base lane (b_e*16)
            #pragma unroll
            for (int jl = 0; jl < 16; ++jl)
                acc += __shfl(p, cbase + jl);
            if (jj_e == 0)
                part[(t * PJ + jgrp) * NB + b0 + b_e] = acc;
        }
        // red_s(t+1) writes happen only after B1(t+1), which wave 0 gates ->
        // no race with the reads above. No further barrier needed.
    }
}

__global__ void pz_kernel(const float* __restrict__ part,
                          const float* __restrict__ noise,
                          const float* __restrict__ b_z,
                          float* __restrict__ out)
{
    int idx = blockIdx.x * blockDim.x + threadIdx.x;  // t*64 + b
    if (idx >= TT * NB) return;
    int t = idx >> 6, b = idx & 63;
    float s = b_z[0];
    #pragma unroll
    for (int jg = 0; jg < PJ; ++jg) s += part[(t * PJ + jg) * NB + b];
    float pz = 1.f / (1.f + expf(-s));
    out[idx] = pz;
    out[TT * NB + idx] = (noise[idx] < pz) ? 1.f : 0.f;
}

// One block per batch column: stable compaction of tokens where z==1.
__global__ void compact_kernel(const int* __restrict__ sent,
                               const float* __restrict__ zbuf,
                               float* __restrict__ rat,
                               float* __restrict__ zsz)
{
    __shared__ float rat_s[TT];
    __shared__ int scan_s[256];
    int b = blockIdx.x, tid = threadIdx.x;
    int zloc[8];
    int base = tid * 8;
    int c = 0;
    #pragma unroll
    for (int i = 0; i < 8; ++i) {
        zloc[i] = (zbuf[(base + i) * NB + b] != 0.f) ? 1 : 0;
        c += zloc[i];
    }
    scan_s[tid] = c;
    for (int i = tid; i < TT; i += 256) rat_s[i] = 0.f;
    __syncthreads();
    for (int off = 1; off < 256; off <<= 1) {
        int v = scan_s[tid];
        int add = (tid >= off) ? scan_s[tid - off] : 0;
        __syncthreads();
        scan_s[tid] = v + add;
        __syncthreads();
    }
    int total = scan_s[255];
    int pos = scan_s[tid] - c;  // exclusive prefix
    #pragma unroll
    for (int i = 0; i < 8; ++i) {
        if (zloc[i]) { rat_s[pos] = (float)sent[(base + i) * NB + b]; ++pos; }
    }
    __syncthreads();
    for (int i = tid; i < TT; i += 256) rat[i * NB + b] = rat_s[i];
    if (tid == 0) zsz[b] = (float)total;
}

extern "C" void kernel_launch(void* const* d_in, const int* in_sizes, int n_in,
                              void* d_out, int out_size, void* d_ws, size_t ws_size,
                              hipStream_t stream)
{
    const int*   sent  = (const int*)d_in[0];
    const float* noise = (const float*)d_in[1];
    const float* emb   = (const float*)d_in[2];
    const float* W_ih  = (const float*)d_in[3];
    const float* W_hh  = (const float*)d_in[4];
    const float* b_ih  = (const float*)d_in[5];
    const float* b_hh  = (const float*)d_in[6];
    const float* W_z   = (const float*)d_in[7];
    const float* b_z   = (const float*)d_in[8];
    float* out = (float*)d_out;

    char* ws = (char*)d_ws;
    unsigned long long* hbuf = (unsigned long long*)ws;     // 2*64*256*8 = 256 KB
    float* part = (float*)(ws + 262144);                    // 2048*16*64*4 = 8 MB

    // tags must start != any expected tag (1..2048)
    hipMemsetAsync(hbuf, 0, 2 * NB * HH * sizeof(unsigned long long), stream);

    lstm_kernel<<<256, 256, 0, stream>>>(sent, emb, W_ih, W_hh, b_ih, b_hh, W_z,
                                         hbuf, part);
    pz_kernel<<<(TT * NB) / 256, 256, 0, stream>>>(part, noise, b_z, out);
    compact_kernel<<<NB, 256, 0, stream>>>(sent, out + TT * NB,
                                           out + 2 * TT * NB, out + 3 * TT * NB);
}